// Round 7
// baseline (568.478 us; speedup 1.0000x reference)
//
#include <hip/hip_runtime.h>

// GraphAttentionLayer: B=16, N=2048, F_IN=256, H=128 (fp32 in/out, adj int32)
//  k_pack  : adj int32 -> 1 bit/entry (268 MB -> 8.4 MB), pure HBM stream
//  k_wsplit: W fp32 -> hi/lo bf16 (done once, L2-resident)
//  k_wh    : MFMA bf16x3-split GEMM wh = X@W^T + bW; stages only X in LDS,
//            W-frags direct from L2; fused src/dst dots + bf16 wh_T out
//  k_attn  : barrier-free streaming attention: adj bits in LDS, A-frag (exp
//            weights) computed per-wave in registers, B-frags direct from
//            L2-resident whbT, softmax normalization in epilogue.

#define BDIM 16
#define NDIM 2048
#define FIN 256
#define HDIM 128

typedef short short8 __attribute__((ext_vector_type(8)));
typedef float floatx4 __attribute__((ext_vector_type(4)));

__device__ __forceinline__ unsigned short f2bf(float x) {
    unsigned int u = __float_as_uint(x);
    unsigned int r = (u + 0x7fffu + ((u >> 16) & 1u)) >> 16;  // RNE
    return (unsigned short)r;
}
__device__ __forceinline__ float bf2f(unsigned short s) {
    return __uint_as_float(((unsigned int)s) << 16);
}

// ---------------- k_pack: adjacency bit-packing ----------------
// one thread per 32 consecutive entries; 8192 blocks
__global__ __launch_bounds__(256) void k_pack(const int* __restrict__ adj,
                                              unsigned int* __restrict__ packed) {
    const size_t gid = (size_t)blockIdx.x * 256 + threadIdx.x;
    const int4* p = reinterpret_cast<const int4*>(adj + gid * 32);
    unsigned int bits = 0;
    #pragma unroll
    for (int k = 0; k < 8; k++) {
        int4 v = p[k];
        bits |= (v.x > 0 ? (1u << (4 * k + 0)) : 0u);
        bits |= (v.y > 0 ? (1u << (4 * k + 1)) : 0u);
        bits |= (v.z > 0 ? (1u << (4 * k + 2)) : 0u);
        bits |= (v.w > 0 ? (1u << (4 * k + 3)) : 0u);
    }
    packed[gid] = bits;
}

// ---------------- k_wsplit: W -> hi/lo bf16 ----------------
__global__ __launch_bounds__(256) void k_wsplit(const float* __restrict__ W,
                                                unsigned short* __restrict__ Whi,
                                                unsigned short* __restrict__ Wlo) {
    const int gid = blockIdx.x * 256 + threadIdx.x;   // 8192 float4s
    float4 v = reinterpret_cast<const float4*>(W)[gid];
    union { unsigned short s[4]; uint2 u; } h, l;
    h.s[0] = f2bf(v.x); l.s[0] = f2bf(v.x - bf2f(h.s[0]));
    h.s[1] = f2bf(v.y); l.s[1] = f2bf(v.y - bf2f(h.s[1]));
    h.s[2] = f2bf(v.z); l.s[2] = f2bf(v.z - bf2f(h.s[2]));
    h.s[3] = f2bf(v.w); l.s[3] = f2bf(v.w - bf2f(h.s[3]));
    reinterpret_cast<uint2*>(Whi)[gid] = h.u;
    reinterpret_cast<uint2*>(Wlo)[gid] = l.u;
}

// ---------------- k_wh: wh GEMM via MFMA (bf16 hi/lo split) ----------------
// 64 rows x 128 h per block; X staged hi/lo in LDS per 64-K panel; W from L2.
__global__ __launch_bounds__(256) void k_wh(const float* __restrict__ X,
                                            const unsigned short* __restrict__ Whi,
                                            const unsigned short* __restrict__ Wlo,
                                            const float* __restrict__ bW,
                                            const float* __restrict__ a,
                                            float* __restrict__ src,
                                            float* __restrict__ dst,
                                            unsigned short* __restrict__ whbT) {
    __shared__ short lds[9216];                    // 18 KB
    short (*xh)[72] = (short(*)[72])lds;           // [64][72]
    short (*xl)[72] = (short(*)[72])(lds + 4608);  // [64][72]
    short (*tb)[72] = (short(*)[72])lds;           // epilogue alias [128][72]

    const int tid = threadIdx.x;
    const long row0 = (long)blockIdx.x * 64;
    const int w = tid >> 6, lane = tid & 63;
    const int lm = lane & 15, q = lane >> 4;

    float a1v[8], a2v[8], bwv[8];
    #pragma unroll
    for (int nt = 0; nt < 8; nt++) {
        a1v[nt] = a[nt * 16 + lm];
        a2v[nt] = a[HDIM + nt * 16 + lm];
        bwv[nt] = bW[nt * 16 + lm];
    }

    floatx4 acc[8];
    #pragma unroll
    for (int nt = 0; nt < 8; nt++) acc[nt] = (floatx4){0.f, 0.f, 0.f, 0.f};

    for (int k0 = 0; k0 < FIN; k0 += 64) {
        // stage X panel hi/lo
        #pragma unroll
        for (int u = 0; u < 4; u++) {
            int idx = tid + u * 256;            // 1024 float4 chunks
            int r = idx >> 4, fc = (idx & 15) * 4;
            float4 v = *reinterpret_cast<const float4*>(X + (row0 + r) * FIN + k0 + fc);
            union { unsigned short s[4]; uint2 u2; } ph, pl;
            ph.s[0] = f2bf(v.x); pl.s[0] = f2bf(v.x - bf2f(ph.s[0]));
            ph.s[1] = f2bf(v.y); pl.s[1] = f2bf(v.y - bf2f(ph.s[1]));
            ph.s[2] = f2bf(v.z); pl.s[2] = f2bf(v.z - bf2f(ph.s[2]));
            ph.s[3] = f2bf(v.w); pl.s[3] = f2bf(v.w - bf2f(ph.s[3]));
            *reinterpret_cast<uint2*>(&xh[r][fc]) = ph.u2;
            *reinterpret_cast<uint2*>(&xl[r][fc]) = pl.u2;
        }
        __syncthreads();
        #pragma unroll
        for (int ks = 0; ks < 64; ks += 32) {
            short8 afh = *reinterpret_cast<const short8*>(&xh[w * 16 + lm][ks + q * 8]);
            short8 afl = *reinterpret_cast<const short8*>(&xl[w * 16 + lm][ks + q * 8]);
            #pragma unroll
            for (int nt = 0; nt < 8; nt++) {
                const size_t woff = (size_t)(nt * 16 + lm) * FIN + k0 + ks + q * 8;
                short8 bfh = *reinterpret_cast<const short8*>(Whi + woff);
                short8 bfl = *reinterpret_cast<const short8*>(Wlo + woff);
                acc[nt] = __builtin_amdgcn_mfma_f32_16x16x32_bf16(afh, bfh, acc[nt], 0, 0, 0);
                acc[nt] = __builtin_amdgcn_mfma_f32_16x16x32_bf16(afh, bfl, acc[nt], 0, 0, 0);
                acc[nt] = __builtin_amdgcn_mfma_f32_16x16x32_bf16(afl, bfh, acc[nt], 0, 0, 0);
            }
        }
        __syncthreads();
    }

    // epilogue: bias, src/dst dots, bf16 transpose via LDS (tb aliases xh/xl)
    float s1[4] = {0.f, 0.f, 0.f, 0.f}, s2[4] = {0.f, 0.f, 0.f, 0.f};
    #pragma unroll
    for (int nt = 0; nt < 8; nt++) {
        #pragma unroll
        for (int r = 0; r < 4; r++) {
            float v = acc[nt][r] + bwv[nt];
            s1[r] += v * a1v[nt];
            s2[r] += v * a2v[nt];
            tb[nt * 16 + lm][w * 16 + q * 4 + r] = f2bf(v);
        }
    }
    #pragma unroll
    for (int r = 0; r < 4; r++) {
        #pragma unroll
        for (int o = 1; o < 16; o <<= 1) {
            s1[r] += __shfl_xor(s1[r], o);
            s2[r] += __shfl_xor(s2[r], o);
        }
    }
    if (lm == 0) {
        #pragma unroll
        for (int r = 0; r < 4; r++) {
            long row = row0 + w * 16 + q * 4 + r;
            src[row] = s1[r];
            dst[row] = s2[r];
        }
    }
    __syncthreads();
    const int b = (int)(row0 >> 11);
    const int n0 = (int)(row0 & 2047);
    #pragma unroll
    for (int u = 0; u < 4; u++) {
        int idx = tid + u * 256;
        int hh = idx >> 3, c = idx & 7;
        *reinterpret_cast<uint4*>(whbT + ((size_t)(b * HDIM + hh)) * NDIM + n0 + c * 8) =
            *reinterpret_cast<const uint4*>(&tb[hh][c * 8]);
    }
}

// ---------------- k_attn: barrier-free streaming MFMA attention ----------------
// TI=32 i-rows x full H per block (1024 blocks). Wave w: i-half ib=(w&1)*16,
// h-half hb=(w>>1)*64. A-frag (exp weights) computed in registers per wave
// (x2 duplication across h-halves); adj bits from LDS; B/dst from L2.
__global__ __launch_bounds__(256) void k_attn(const unsigned int* __restrict__ packed,
                                              const unsigned short* __restrict__ whbT,
                                              const float* __restrict__ src,
                                              const float* __restrict__ dst,
                                              const float* __restrict__ ba_p,
                                              float* __restrict__ out) {
    __shared__ unsigned int awords[32][65];   // 8.3 KB, pad 65 -> conflict-free
    __shared__ float lred[32];
    __shared__ float linv_s[32];

    const int tid = threadIdx.x;
    const int b = blockIdx.x >> 6;            // 64 i-tiles per batch
    const int i0 = (blockIdx.x & 63) * 32;

    // preamble: stage packed-adj rows i0..i0+31 (2048 words, coalesced)
    {
        const uint4* pp = reinterpret_cast<const uint4*>(packed + ((size_t)(b * NDIM + i0)) * 64);
        uint4 w0 = pp[tid * 2], w1 = pp[tid * 2 + 1];
        int r = tid >> 3, c = (tid & 7) * 8;
        awords[r][c + 0] = w0.x; awords[r][c + 1] = w0.y;
        awords[r][c + 2] = w0.z; awords[r][c + 3] = w0.w;
        awords[r][c + 4] = w1.x; awords[r][c + 5] = w1.y;
        awords[r][c + 6] = w1.z; awords[r][c + 7] = w1.w;
    }

    const int wave = tid >> 6, lane = tid & 63;
    const int lm = lane & 15, q = lane >> 4;
    const int ib = (wave & 1) * 16;
    const int hb = (wave >> 1) * 64;

    const float si = src[b * NDIM + i0 + ib + lm] + ba_p[0];
    const float* dstb = dst + b * NDIM;
    const unsigned short* bbase =
        whbT + (size_t)b * HDIM * NDIM + (size_t)(hb + lm) * NDIM + q * 8;

    floatx4 acc[4];
    #pragma unroll
    for (int hj = 0; hj < 4; hj++) acc[hj] = (floatx4){0.f, 0.f, 0.f, 0.f};
    float lpart = 0.f;
    __syncthreads();

    #pragma unroll 2
    for (int t = 0; t < NDIM / 32; t++) {
        const int jc = t * 32;
        const unsigned int word = awords[ib + lm][t];
        const unsigned int byte = (word >> (q * 8)) & 0xffu;
        float4 d0 = *reinterpret_cast<const float4*>(dstb + jc + q * 8);
        float4 d1 = *reinterpret_cast<const float4*>(dstb + jc + q * 8 + 4);
        float ev[8] = {d0.x, d0.y, d0.z, d0.w, d1.x, d1.y, d1.z, d1.w};
        unsigned short wb[8];
        float ls = 0.f;
        #pragma unroll
        for (int j = 0; j < 8; j++) {
            float x = si + ev[j];
            x = x > 0.f ? x : 0.01f * x;
            float wgt = ((byte >> j) & 1u) ? __expf(x) : 0.f;
            ls += wgt;
            wb[j] = f2bf(wgt);
        }
        lpart += ls;
        short8 af = *reinterpret_cast<const short8*>(wb);
        #pragma unroll
        for (int hj = 0; hj < 4; hj++) {
            short8 bfr = *reinterpret_cast<const short8*>(bbase + (size_t)hj * 16 * NDIM + jc);
            acc[hj] = __builtin_amdgcn_mfma_f32_16x16x32_bf16(af, bfr, acc[hj], 0, 0, 0);
        }
    }

    // row sums: lanes with same lm differ in bits 4,5 (q); waves 0,1 cover rows
    lpart += __shfl_xor(lpart, 16);
    lpart += __shfl_xor(lpart, 32);
    if (wave < 2 && lane < 16) lred[ib + lane] = lpart;
    __syncthreads();
    if (tid < 32) {
        float l = lred[tid];
        linv_s[tid] = l > 0.f ? 1.f / l : 0.f;
    }
    __syncthreads();

    // epilogue: scale by 1/l, ELU, store (C/D: col=lm, row=q*4+r)
    #pragma unroll
    for (int r = 0; r < 4; r++) {
        int il = ib + q * 4 + r;
        float li = linv_s[il];
        long obase = ((long)(b * NDIM + i0 + il)) * HDIM + hb + lm;
        #pragma unroll
        for (int hj = 0; hj < 4; hj++) {
            float x = acc[hj][r] * li;
            x = x > 0.f ? x : (__expf(x) - 1.f);
            out[obase + hj * 16] = x;
        }
    }
}

extern "C" void kernel_launch(void* const* d_in, const int* in_sizes, int n_in,
                              void* d_out, int out_size, void* d_ws, size_t ws_size,
                              hipStream_t stream) {
    const float* X  = (const float*)d_in[0];   // [16,2048,256]
    const int* adj  = (const int*)d_in[1];     // [16,2048,2048]
    const float* W  = (const float*)d_in[2];   // [128,256]
    const float* bW = (const float*)d_in[3];   // [128]
    const float* a  = (const float*)d_in[4];   // [1,256]
    const float* ba = (const float*)d_in[5];   // [1]
    float* out = (float*)d_out;                // [16,2048,128]

    float* srcv = (float*)d_ws;                                     // 32768 f
    float* dstv = srcv + BDIM * NDIM;                               // 32768 f
    unsigned short* whbT = (unsigned short*)(dstv + BDIM * NDIM);   // 8.4 MB bf16
    unsigned int* packed = (unsigned int*)(whbT + (size_t)BDIM * HDIM * NDIM);  // 8.4 MB
    unsigned short* Whi = (unsigned short*)(packed + (size_t)BDIM * NDIM * (NDIM / 32));
    unsigned short* Wlo = Whi + HDIM * FIN;

    k_wsplit<<<32, 256, 0, stream>>>(W, Whi, Wlo);
    k_pack<<<(BDIM * NDIM * (NDIM / 32)) / 256, 256, 0, stream>>>(adj, packed);
    k_wh<<<BDIM * NDIM / 64, 256, 0, stream>>>(X, Whi, Wlo, bW, a, srcv, dstv, whbT);
    k_attn<<<BDIM * (NDIM / 32), 256, 0, stream>>>(packed, whbT, srcv, dstv, ba, out);
}

// Round 8
// 433.945 us; speedup vs baseline: 1.3100x; 1.3100x over previous
//
#include <hip/hip_runtime.h>

// GraphAttentionLayer: B=16, N=2048, F_IN=256, H=128 (fp32 in/out, adj int32)
//  k_wh  : MFMA bf16x3-split GEMM wh = X@W^T + bW (X,W staged in LDS);
//          fused src/dst dots; writes wh in MFMA B-FRAGMENT order:
//          whF[b][jc][ht][lane][e] = wh[b][jc*32+(lane>>4)*8+e][ht*16+(lane&15)]
//  k_attn: barrier-free attention. Each wave owns 16 i-rows x all 128 h.
//          Per 32-j chunk: adj (HBM, reg-prefetch) -> exp weights -> A-frag in
//          regs; B-frags loaded COALESCED from whF (L2); 8 MFMAs. No LDS/bar
//          in loop. Softmax normalization folded into epilogue (1/l scale).

#define BDIM 16
#define NDIM 2048
#define FIN 256
#define HDIM 128

typedef short short8 __attribute__((ext_vector_type(8)));
typedef float floatx4 __attribute__((ext_vector_type(4)));

__device__ __forceinline__ unsigned short f2bf(float x) {
    unsigned int u = __float_as_uint(x);
    unsigned int r = (u + 0x7fffu + ((u >> 16) & 1u)) >> 16;  // RNE
    return (unsigned short)r;
}
__device__ __forceinline__ float bf2f(unsigned short s) {
    return __uint_as_float(((unsigned int)s) << 16);
}

// ---------------- Kernel 1: wh via MFMA (bf16 hi/lo split) ----------------
// 64 rows x 128 h per block; 4 waves = 4 m-tiles of 16; K in panels of 64.
__global__ __launch_bounds__(256) void k_wh(const float* __restrict__ X,
                                            const float* __restrict__ W,
                                            const float* __restrict__ bW,
                                            const float* __restrict__ a,
                                            float* __restrict__ src,
                                            float* __restrict__ dst,
                                            unsigned short* __restrict__ whF) {
    __shared__ short lds[27648];                    // 54 KB
    short (*ah)[72] = (short(*)[72])lds;
    short (*al)[72] = (short(*)[72])(lds + 4608);
    short (*bh)[72] = (short(*)[72])(lds + 9216);
    short (*bl)[72] = (short(*)[72])(lds + 18432);
    short (*tb)[72] = (short(*)[72])lds;            // epilogue alias [128][72]

    const int tid = threadIdx.x;
    const long row0 = (long)blockIdx.x * 64;
    const int w = tid >> 6, lane = tid & 63;
    const int lm = lane & 15, q = lane >> 4;

    float a1v[8], a2v[8], bwv[8];
    #pragma unroll
    for (int nt = 0; nt < 8; nt++) {
        a1v[nt] = a[nt * 16 + lm];
        a2v[nt] = a[HDIM + nt * 16 + lm];
        bwv[nt] = bW[nt * 16 + lm];
    }

    floatx4 acc[8];
    #pragma unroll
    for (int nt = 0; nt < 8; nt++) acc[nt] = (floatx4){0.f, 0.f, 0.f, 0.f};

    for (int k0 = 0; k0 < FIN; k0 += 64) {
        #pragma unroll
        for (int u = 0; u < 4; u++) {
            int idx = tid + u * 256;
            int r = idx >> 4, fc = (idx & 15) * 4;
            float4 v = *reinterpret_cast<const float4*>(X + (row0 + r) * FIN + k0 + fc);
            union { unsigned short s[4]; uint2 u2; } ph, pl;
            ph.s[0] = f2bf(v.x); pl.s[0] = f2bf(v.x - bf2f(ph.s[0]));
            ph.s[1] = f2bf(v.y); pl.s[1] = f2bf(v.y - bf2f(ph.s[1]));
            ph.s[2] = f2bf(v.z); pl.s[2] = f2bf(v.z - bf2f(ph.s[2]));
            ph.s[3] = f2bf(v.w); pl.s[3] = f2bf(v.w - bf2f(ph.s[3]));
            *reinterpret_cast<uint2*>(&ah[r][fc]) = ph.u2;
            *reinterpret_cast<uint2*>(&al[r][fc]) = pl.u2;
        }
        #pragma unroll
        for (int u = 0; u < 8; u++) {
            int idx = tid + u * 256;
            int hh = idx >> 4, fc = (idx & 15) * 4;
            float4 v = *reinterpret_cast<const float4*>(W + hh * FIN + k0 + fc);
            union { unsigned short s[4]; uint2 u2; } ph, pl;
            ph.s[0] = f2bf(v.x); pl.s[0] = f2bf(v.x - bf2f(ph.s[0]));
            ph.s[1] = f2bf(v.y); pl.s[1] = f2bf(v.y - bf2f(ph.s[1]));
            ph.s[2] = f2bf(v.z); pl.s[2] = f2bf(v.z - bf2f(ph.s[2]));
            ph.s[3] = f2bf(v.w); pl.s[3] = f2bf(v.w - bf2f(ph.s[3]));
            *reinterpret_cast<uint2*>(&bh[hh][fc]) = ph.u2;
            *reinterpret_cast<uint2*>(&bl[hh][fc]) = pl.u2;
        }
        __syncthreads();
        #pragma unroll
        for (int ks = 0; ks < 64; ks += 32) {
            short8 afh = *reinterpret_cast<const short8*>(&ah[w * 16 + lm][ks + q * 8]);
            short8 afl = *reinterpret_cast<const short8*>(&al[w * 16 + lm][ks + q * 8]);
            #pragma unroll
            for (int nt = 0; nt < 8; nt++) {
                short8 bfh = *reinterpret_cast<const short8*>(&bh[nt * 16 + lm][ks + q * 8]);
                short8 bfl = *reinterpret_cast<const short8*>(&bl[nt * 16 + lm][ks + q * 8]);
                acc[nt] = __builtin_amdgcn_mfma_f32_16x16x32_bf16(afh, bfh, acc[nt], 0, 0, 0);
                acc[nt] = __builtin_amdgcn_mfma_f32_16x16x32_bf16(afh, bfl, acc[nt], 0, 0, 0);
                acc[nt] = __builtin_amdgcn_mfma_f32_16x16x32_bf16(afl, bfh, acc[nt], 0, 0, 0);
            }
        }
        __syncthreads();
    }

    // epilogue: bias, src/dst dots, transpose via LDS -> B-fragment layout
    float s1[4] = {0.f, 0.f, 0.f, 0.f}, s2[4] = {0.f, 0.f, 0.f, 0.f};
    #pragma unroll
    for (int nt = 0; nt < 8; nt++) {
        #pragma unroll
        for (int r = 0; r < 4; r++) {
            float v = acc[nt][r] + bwv[nt];
            s1[r] += v * a1v[nt];
            s2[r] += v * a2v[nt];
            tb[nt * 16 + lm][w * 16 + q * 4 + r] = f2bf(v);   // tb[h][jrel]
        }
    }
    #pragma unroll
    for (int r = 0; r < 4; r++) {
        #pragma unroll
        for (int o = 1; o < 16; o <<= 1) {
            s1[r] += __shfl_xor(s1[r], o);
            s2[r] += __shfl_xor(s2[r], o);
        }
    }
    if (lm == 0) {
        #pragma unroll
        for (int r = 0; r < 4; r++) {
            long row = row0 + w * 16 + q * 4 + r;
            src[row] = s1[r];
            dst[row] = s2[r];
        }
    }
    __syncthreads();
    // whF[b][jc][ht][l][e], frag = 512 shorts; block covers jc0..jc0+1
    const int b = (int)(row0 >> 11);
    const int jc0 = (int)((row0 & 2047) >> 5);
    const int f = tid >> 4;          // 0..15: jcrel = f>>3, ht = f&7
    const int sub = tid & 15;
    const int jcrel = f >> 3, ht = f & 7;
    const size_t fbase = (((size_t)b * 64 + jc0 + jcrel) * 8 + ht) * 512;
    #pragma unroll
    for (int i = 0; i < 4; i++) {
        int l = sub * 4 + i;
        uint4 v = *reinterpret_cast<const uint4*>(&tb[ht * 16 + (l & 15)][jcrel * 32 + (l >> 4) * 8]);
        *reinterpret_cast<uint4*>(whF + fbase + l * 8) = v;
    }
}

// ---------------- Kernel 2: barrier-free streaming MFMA attention ----------------
// 512 blocks; wave w owns i-rows i0+w*16..+15 (x all 128 h). No LDS/bar in loop.
__global__ __launch_bounds__(256) void k_attn(const int* __restrict__ adj,
                                              const unsigned short* __restrict__ whF,
                                              const float* __restrict__ src,
                                              const float* __restrict__ dst,
                                              const float* __restrict__ ba_p,
                                              float* __restrict__ out) {
    __shared__ float lred[64];
    __shared__ float linv_s[64];

    const int tid = threadIdx.x;
    const int b = blockIdx.x >> 5;            // 32 i-tiles per batch
    const int i0 = (blockIdx.x & 31) * 64;
    const int wave = tid >> 6, lane = tid & 63;
    const int lm = lane & 15, q = lane >> 4;
    const int irow = i0 + wave * 16 + lm;

    const float si = src[b * NDIM + irow] + ba_p[0];
    const int* adjp = adj + ((size_t)(b * NDIM + irow)) * NDIM + q * 8;
    const float* dstp = dst + b * NDIM + q * 8;
    const unsigned short* whFb = whF + (size_t)b * 64 * 8 * 512 + lane * 8;

    floatx4 acc[8];
    #pragma unroll
    for (int hj = 0; hj < 8; hj++) acc[hj] = (floatx4){0.f, 0.f, 0.f, 0.f};
    float lpart = 0.f;

    int4 m[2][2];
    float4 d[2][2];
    short8 bfr[2][8];
    // prefetch chunk 0 -> slot 0
    m[0][0] = *reinterpret_cast<const int4*>(adjp);
    m[0][1] = *reinterpret_cast<const int4*>(adjp + 4);
    d[0][0] = *reinterpret_cast<const float4*>(dstp);
    d[0][1] = *reinterpret_cast<const float4*>(dstp + 4);
    #pragma unroll
    for (int hj = 0; hj < 8; hj++) bfr[0][hj] = *reinterpret_cast<const short8*>(whFb + hj * 512);

    #pragma unroll 2
    for (int t = 0; t < NDIM / 32; t++) {
        const int p = t & 1, pn = p ^ 1;
        if (t + 1 < NDIM / 32) {   // issue next-chunk loads first (stay in flight)
            const int* ap = adjp + (t + 1) * 32;
            m[pn][0] = *reinterpret_cast<const int4*>(ap);
            m[pn][1] = *reinterpret_cast<const int4*>(ap + 4);
            const float* dp = dstp + (t + 1) * 32;
            d[pn][0] = *reinterpret_cast<const float4*>(dp);
            d[pn][1] = *reinterpret_cast<const float4*>(dp + 4);
            const unsigned short* wp = whFb + (size_t)(t + 1) * 8 * 512;
            #pragma unroll
            for (int hj = 0; hj < 8; hj++)
                bfr[pn][hj] = *reinterpret_cast<const short8*>(wp + hj * 512);
        }
        // A-frag: A[m=lm][k=q*8+j] = exp weight for (row irow, col t*32+q*8+j)
        const int* mi = reinterpret_cast<const int*>(&m[p][0]);
        const float* df = reinterpret_cast<const float*>(&d[p][0]);
        unsigned short wb[8];
        float ls = 0.f;
        #pragma unroll
        for (int j = 0; j < 8; j++) {
            float x = si + df[j];
            x = x > 0.f ? x : 0.01f * x;
            float wgt = mi[j] > 0 ? __expf(x) : 0.f;
            ls += wgt;
            wb[j] = f2bf(wgt);
        }
        lpart += ls;
        short8 af = *reinterpret_cast<const short8*>(wb);
        #pragma unroll
        for (int hj = 0; hj < 8; hj++)
            acc[hj] = __builtin_amdgcn_mfma_f32_16x16x32_bf16(af, bfr[p][hj], acc[hj], 0, 0, 0);
    }

    // denominator: combine the 4 q-slices of each row
    lpart += __shfl_xor(lpart, 16);
    lpart += __shfl_xor(lpart, 32);
    if (q == 0) lred[wave * 16 + lm] = lpart;
    __syncthreads();
    if (tid < 64) {
        float l = lred[tid];
        linv_s[tid] = l > 0.f ? 1.f / l : 0.f;
    }
    __syncthreads();

    // epilogue: scale 1/l, ELU, store (C/D: col=lm -> h, row=q*4+r -> i)
    #pragma unroll
    for (int r = 0; r < 4; r++) {
        int il = wave * 16 + q * 4 + r;
        float li = linv_s[il];
        size_t obase = ((size_t)(b * NDIM + i0 + il)) * HDIM + lm;
        #pragma unroll
        for (int hj = 0; hj < 8; hj++) {
            float x = acc[hj][r] * li;
            x = x > 0.f ? x : (__expf(x) - 1.f);
            out[obase + hj * 16] = x;
        }
    }
}

extern "C" void kernel_launch(void* const* d_in, const int* in_sizes, int n_in,
                              void* d_out, int out_size, void* d_ws, size_t ws_size,
                              hipStream_t stream) {
    const float* X  = (const float*)d_in[0];   // [16,2048,256]
    const int* adj  = (const int*)d_in[1];     // [16,2048,2048]
    const float* W  = (const float*)d_in[2];   // [128,256]
    const float* bW = (const float*)d_in[3];   // [128]
    const float* a  = (const float*)d_in[4];   // [1,256]
    const float* ba = (const float*)d_in[5];   // [1]
    float* out = (float*)d_out;                // [16,2048,128]

    float* srcv = (float*)d_ws;                                    // B*N
    float* dstv = srcv + BDIM * NDIM;                              // B*N
    unsigned short* whF = (unsigned short*)(dstv + BDIM * NDIM);   // 8.4 MB bf16 frag-order

    k_wh<<<BDIM * NDIM / 64, 256, 0, stream>>>(X, W, bW, a, srcv, dstv, whF);
    k_attn<<<BDIM * (NDIM / 64), 256, 0, stream>>>(adj, whF, srcv, dstv, ba, out);
}